// Round 10
// baseline (875.197 us; speedup 1.0000x reference)
//
#include <hip/hip_runtime.h>
#include <hip/hip_bf16.h>

#define N_NODES 50000
#define NPAD    50048
#define N_EDGES 800000
#define EDIM 26
#define DXF 28
#define G_GRAPHS 64
#define NQ 2048
#define MARG 1.2f
#define CHUNK 8

typedef __attribute__((ext_vector_type(8))) short short8v;
typedef __attribute__((ext_vector_type(4))) float f32x4;
typedef unsigned short u16;
typedef unsigned int u32;

__device__ __forceinline__ float leakyf(float x){ return x >= 0.f ? x : 0.01f*x; }
__device__ __forceinline__ u16 f2bf(float f){
  __hip_bfloat16 h = __float2bfloat16(f);
  return __builtin_bit_cast(u16, h);
}
__device__ __forceinline__ float bf2f(u16 u){
  return __builtin_bit_cast(float, (u32)u << 16);
}
__device__ __forceinline__ u32 packbf(float a, float b){
  return (u32)f2bf(a) | ((u32)f2bf(b) << 16);
}
__device__ __forceinline__ float lo16(u32 v){ return __builtin_bit_cast(float, v << 16); }
__device__ __forceinline__ float hi16(u32 v){ return __builtin_bit_cast(float, v & 0xffff0000u); }

// ---------------------------------------------------------------------------
// init: fused prep (weight packing) + tfs (edge-logit table) + hist.
// block ranges: [0,436) prep, [436,6580) tfs, [6580,9705) hist.
// ---------------------------------------------------------------------------
__global__ __launch_bounds__(256) void init_kernel(
    const float* __restrict__ cwf, const float* __restrict__ cws,
    const float* __restrict__ cbf, const float* __restrict__ cbs,
    const float* __restrict__ ew1, const float* __restrict__ ew2,
    const float* __restrict__ ew3,
    const int* __restrict__ ei,
    u16* __restrict__ Wpk, u16* __restrict__ w1pk,
    u16* __restrict__ w2pk, u16* __restrict__ w3pk,
    u32* __restrict__ TFS, int* __restrict__ cnt)
{
  const int b = blockIdx.x;
  if (b < 436){
    int tid = b*256 + threadIdx.x;
    u16 out[8];
    if (tid < 98304){
      int nn  = tid & 1023;
      int kb  = (tid >> 10) & 31;
      int lyr = tid >> 15;
      int side = nn >> 9, g = (nn >> 4) & 31, r = nn & 15;
      int type = g & 1, ch = (g >> 1)*16 + r;
      const float* W = (type ? cws : cwf) + (size_t)lyr*538*256;
      #pragma unroll
      for (int j=0;j<8;j++)
        out[j] = f2bf(W[(size_t)(side*256 + kb*8 + j)*256 + ch]);
      *reinterpret_cast<uint4*>(&Wpk[(size_t)tid*8]) = *reinterpret_cast<uint4*>(out);
    } else if (tid < 99328){
      int i = tid - 98304;  int kq = i >> 8, col = i & 255;
      #pragma unroll
      for (int j=0;j<8;j++) out[j] = f2bf(ew1[(kq*8+j)*256 + col]);
      *reinterpret_cast<uint4*>(&w1pk[(size_t)i*8]) = *reinterpret_cast<uint4*>(out);
    } else if (tid < 107520){
      int i = tid - 99328;  int kb = i >> 8, col = i & 255;
      #pragma unroll
      for (int j=0;j<8;j++) out[j] = f2bf(ew2[(kb*8+j)*256 + col]);
      *reinterpret_cast<uint4*>(&w2pk[(size_t)i*8]) = *reinterpret_cast<uint4*>(out);
    } else if (tid < 111616){
      int i = tid - 107520; int kb = i >> 7, col = i & 127;
      #pragma unroll
      for (int j=0;j<8;j++) out[j] = f2bf(ew3[(kb*8+j)*128 + col]);
      *reinterpret_cast<uint4*>(&w3pk[(size_t)i*8]) = *reinterpret_cast<uint4*>(out);
    }
  } else if (b < 6580){
    int bi = b - 436;
    int q = bi & (NQ-1);
    int lyr = bi >> 11;
    int c = threadIdx.x;
    const float* wf = cwf + (size_t)lyr*538*256 + (size_t)512*256;
    const float* ws = cws + (size_t)lyr*538*256 + (size_t)512*256;
    float f = cbf[lyr*256 + c], s = cbs[lyr*256 + c];
    float len = (float)q * (5.f/NQ);
    for (int k=0;k<EDIM;k++){
      float d = len - 0.2f*(float)k;
      float g = __expf(-25.f*d*d);
      f += g * wf[k*256 + c];
      s += g * ws[k*256 + c];
    }
    TFS[((size_t)lyr*NQ + q)*256 + c] = packbf(f, s);
  } else {
    int e = (b - 6580)*256 + threadIdx.x;
    if (e < N_EDGES) atomicAdd(&cnt[ei[N_EDGES + e]], 1);
  }
}

// ---------------------------------------------------------------------------
// Embed (MFMA): 32 nodes per block (unchanged).
// ---------------------------------------------------------------------------
__global__ __launch_bounds__(256) void embed_kernel(
    const float* __restrict__ x, const float* __restrict__ fs,
    const float* __restrict__ fn, const float* __restrict__ act,
    const u16* __restrict__ w1pk, const float* __restrict__ eb1,
    const u16* __restrict__ w2pk, const float* __restrict__ eb2,
    const u16* __restrict__ w3pk, const float* __restrict__ eb3,
    const float* __restrict__ aw,  const float* __restrict__ ab,
    u16* __restrict__ sB)
{
  __shared__ u16 inA[32*32];
  __shared__ float actS[32*4];
  __shared__ u16 h1[32*256];
  __shared__ u16 h2[32*256];
  const int t = threadIdx.x;
  const int w = t >> 6, l = t & 63, q = l >> 4, r16 = l & 15;
  const int node0 = blockIdx.x * 32;

  for (int idx=t; idx<1024; idx+=256){
    int n = idx >> 5, k = idx & 31;
    int node = node0 + n;
    float v = 0.f;
    if (node < N_NODES){
      if (k < DXF)      v = x[node*DXF + k];
      else if (k < 31)  v = fs[node*3 + (k - DXF)];
      else              v = fn[node];
    }
    inA[idx] = f2bf(v);
  }
  { int n = t >> 2, k = t & 3;
    float v = 0.f;
    if (n < 32 && k < 3 && node0 + n < N_NODES) v = act[(node0+n)*3 + k];
    if (n < 32) actS[t] = v; }
  __syncthreads();

  f32x4 acc[2][4];
  #pragma unroll
  for (int mi=0;mi<2;mi++)
    #pragma unroll
    for (int ni=0;ni<4;ni++){ acc[mi][ni][0]=0;acc[mi][ni][1]=0;acc[mi][ni][2]=0;acc[mi][ni][3]=0; }
  {
    short8v a[2], b[4];
    #pragma unroll
    for (int mi=0;mi<2;mi++)
      a[mi] = *reinterpret_cast<const short8v*>(&inA[(mi*16+r16)*32 + q*8]);
    #pragma unroll
    for (int ni=0;ni<4;ni++)
      b[ni] = *reinterpret_cast<const short8v*>(&w1pk[((size_t)q*256 + w*64 + ni*16 + r16)*8]);
    #pragma unroll
    for (int mi=0;mi<2;mi++)
      #pragma unroll
      for (int ni=0;ni<4;ni++)
        acc[mi][ni] = __builtin_amdgcn_mfma_f32_16x16x32_bf16(a[mi], b[ni], acc[mi][ni], 0,0,0);
  }
  #pragma unroll
  for (int ni=0;ni<4;ni++){
    int col = w*64 + ni*16 + r16;
    float bias = eb1[col];
    #pragma unroll
    for (int mi=0;mi<2;mi++)
      #pragma unroll
      for (int r=0;r<4;r++){
        int row = mi*16 + q*4 + r;
        h1[(row*256 + col) ^ ((row&7)<<3)] = f2bf(leakyf(acc[mi][ni][r] + bias));
      }
  }
  __syncthreads();

  #pragma unroll
  for (int mi=0;mi<2;mi++)
    #pragma unroll
    for (int ni=0;ni<4;ni++){ acc[mi][ni][0]=0;acc[mi][ni][1]=0;acc[mi][ni][2]=0;acc[mi][ni][3]=0; }
  for (int ks=0;ks<8;ks++){
    short8v a[2], b[4];
    #pragma unroll
    for (int mi=0;mi<2;mi++){
      int row = mi*16 + r16;
      a[mi] = *reinterpret_cast<const short8v*>(&h1[(row*256 + ks*32 + q*8) ^ ((row&7)<<3)]);
    }
    #pragma unroll
    for (int ni=0;ni<4;ni++)
      b[ni] = *reinterpret_cast<const short8v*>(&w2pk[((size_t)(ks*4+q)*256 + w*64 + ni*16 + r16)*8]);
    #pragma unroll
    for (int mi=0;mi<2;mi++)
      #pragma unroll
      for (int ni=0;ni<4;ni++)
        acc[mi][ni] = __builtin_amdgcn_mfma_f32_16x16x32_bf16(a[mi], b[ni], acc[mi][ni], 0,0,0);
  }
  #pragma unroll
  for (int ni=0;ni<4;ni++){
    int col = w*64 + ni*16 + r16;
    float bias = eb2[col];
    #pragma unroll
    for (int mi=0;mi<2;mi++)
      #pragma unroll
      for (int r=0;r<4;r++){
        int row = mi*16 + q*4 + r;
        h2[(row*256 + col) ^ ((row&7)<<3)] = f2bf(leakyf(acc[mi][ni][r] + bias));
      }
  }
  __syncthreads();

  if (w < 2){
    #pragma unroll
    for (int mi=0;mi<2;mi++)
      #pragma unroll
      for (int ni=0;ni<4;ni++){ acc[mi][ni][0]=0;acc[mi][ni][1]=0;acc[mi][ni][2]=0;acc[mi][ni][3]=0; }
    for (int ks=0;ks<8;ks++){
      short8v a[2], b[4];
      #pragma unroll
      for (int mi=0;mi<2;mi++){
        int row = mi*16 + r16;
        a[mi] = *reinterpret_cast<const short8v*>(&h2[(row*256 + ks*32 + q*8) ^ ((row&7)<<3)]);
      }
      #pragma unroll
      for (int ni=0;ni<4;ni++)
        b[ni] = *reinterpret_cast<const short8v*>(&w3pk[((size_t)(ks*4+q)*128 + w*64 + ni*16 + r16)*8]);
      #pragma unroll
      for (int mi=0;mi<2;mi++)
        #pragma unroll
        for (int ni=0;ni<4;ni++)
          acc[mi][ni] = __builtin_amdgcn_mfma_f32_16x16x32_bf16(a[mi], b[ni], acc[mi][ni], 0,0,0);
    }
    #pragma unroll
    for (int ni=0;ni<4;ni++){
      int col = w*64 + ni*16 + r16;
      float bias = eb3[col];
      #pragma unroll
      for (int mi=0;mi<2;mi++)
        #pragma unroll
        for (int r=0;r<4;r++){
          int row = mi*16 + q*4 + r;
          sB[(size_t)(node0+row)*256 + col] = f2bf(leakyf(acc[mi][ni][r] + bias));
        }
    }
  } else {
    int c = t - 128;
    float w0 = aw[c], w1 = aw[128+c], w2 = aw[256+c], bb = ab[c];
    for (int n=0;n<32;n++){
      float v = bb + actS[n*4]*w0 + actS[n*4+1]*w1 + actS[n*4+2]*w2;
      sB[(size_t)(node0+n)*256 + 128 + c] = f2bf(v);
    }
  }
}

// ---------------------------------------------------------------------------
// CSR build scans + scatter
// ---------------------------------------------------------------------------
__global__ __launch_bounds__(256) void scan1_kernel(
    const int* __restrict__ cnt, int* __restrict__ rowptr, int* __restrict__ partial){
  __shared__ int sd[256];
  int t = threadIdx.x; int idx = blockIdx.x*256 + t;
  int v = (idx < N_NODES) ? cnt[idx] : 0;
  sd[t] = v; __syncthreads();
  for (int off=1; off<256; off<<=1){
    int x2 = (t>=off) ? sd[t-off] : 0;
    __syncthreads();
    sd[t] += x2; __syncthreads();
  }
  if (idx < N_NODES) rowptr[idx] = sd[t] - v;
  if (t == 255) partial[blockIdx.x] = sd[255];
}

__global__ __launch_bounds__(256) void scan2_kernel(int* __restrict__ partial, int nb){
  __shared__ int sd[256];
  int t = threadIdx.x;
  int v = (t<nb) ? partial[t] : 0;
  sd[t] = v; __syncthreads();
  for (int off=1; off<256; off<<=1){
    int x2 = (t>=off) ? sd[t-off] : 0;
    __syncthreads();
    sd[t] += x2; __syncthreads();
  }
  if (t<nb) partial[t] = sd[t] - v;
}

__global__ __launch_bounds__(256) void scan3_kernel(
    int* __restrict__ rowptr, const int* __restrict__ partial, int* __restrict__ cursor){
  int idx = blockIdx.x*256 + threadIdx.x;
  if (idx < N_NODES){
    int v = rowptr[idx] + partial[blockIdx.x];
    rowptr[idx] = v; cursor[idx] = v;
  }
  if (idx == 0) rowptr[N_NODES] = N_EDGES;
}

__global__ __launch_bounds__(256) void scatter_kernel(
    const int* __restrict__ ei, const float* __restrict__ elen,
    int* __restrict__ cursor, u32* __restrict__ recP)
{
  int e = blockIdx.x*256 + threadIdx.x;
  if (e >= N_EDGES) return;
  int d = ei[N_EDGES + e];
  int pos = atomicAdd(&cursor[d], 1);
  int qq = (int)rintf(elen[e] * ((float)NQ/5.f));
  qq = min(max(qq,0), NQ-1);
  recP[pos] = (u32)ei[e] | ((u32)qq << 16);
}

// ---------------------------------------------------------------------------
// Proj: quadrant MFMA accumulate (64 rows x 256 packed cols), acc = 64 VGPR.
// ---------------------------------------------------------------------------
__device__ __forceinline__ void proj_accum4(
    const u16* __restrict__ sB, const u16* __restrict__ Wl,
    int m0, int side, int nhalf, int w, int q, int r16, f32x4 acc[4][4])
{
  #pragma unroll
  for (int mi=0;mi<4;mi++)
    #pragma unroll
    for (int ni=0;ni<4;ni++){ acc[mi][ni][0]=0;acc[mi][ni][1]=0;acc[mi][ni][2]=0;acc[mi][ni][3]=0; }
  for (int ks=0; ks<8; ks++){
    short8v a[4], b[4];
    #pragma unroll
    for (int mi=0;mi<4;mi++)
      a[mi] = *reinterpret_cast<const short8v*>(&sB[(size_t)(m0+mi*16+r16)*256 + ks*32 + q*8]);
    #pragma unroll
    for (int ni=0;ni<4;ni++)
      b[ni] = *reinterpret_cast<const short8v*>(
        &Wl[((size_t)(ks*4+q)*1024 + side*512 + w*128 + (nhalf*4+ni)*16 + r16)*8]);
    #pragma unroll
    for (int mi=0;mi<4;mi++)
      #pragma unroll
      for (int ni=0;ni<4;ni++)
        acc[mi][ni] = __builtin_amdgcn_mfma_f32_16x16x32_bf16(a[mi], b[ni], acc[mi][ni], 0,0,0);
  }
}

// scale pass: sampled tiles (every 8th), src side only; per-channel absmax.
__global__ __launch_bounds__(256) void proj_scale_kernel(
    const u16* __restrict__ sB, const u16* __restrict__ Wl,
    u32* __restrict__ scaleU)
{
  __shared__ u32 smax[512];
  const int t = threadIdx.x;
  const int w = t >> 6, l = t & 63, q = l >> 4, r16 = l & 15;
  const int m0 = blockIdx.x * 512;
  const int nhalf = blockIdx.y;
  for (int i=t;i<512;i+=256) smax[i] = 0;
  __syncthreads();

  f32x4 acc[4][4];
  proj_accum4(sB, Wl, m0, 1, nhalf, w, q, r16, acc);

  #pragma unroll
  for (int p=0;p<2;p++){
    int ch = w*64 + (nhalf*2+p)*16 + r16;
    float mf = 0.f, ms = 0.f;
    #pragma unroll
    for (int mi=0;mi<4;mi++)
      #pragma unroll
      for (int r=0;r<4;r++){
        mf = fmaxf(mf, fabsf(acc[mi][2*p][r]));
        ms = fmaxf(ms, fabsf(acc[mi][2*p+1][r]));
      }
    atomicMax(&smax[ch],       __float_as_uint(mf));
    atomicMax(&smax[256 + ch], __float_as_uint(ms));
  }
  __syncthreads();
  for (int i=t;i<512;i+=256) atomicMax(&scaleU[i], smax[i]);
}

// main proj: grid (NPAD/64, 4); y>>1 = side (0 dst bf16, 1 src int8), y&1 = n-half.
__global__ __launch_bounds__(256) void proj_main_kernel(
    const u16* __restrict__ sB, const u16* __restrict__ Wl,
    u32* __restrict__ Pdst, u16* __restrict__ Psrc8,
    const u32* __restrict__ scaleU)
{
  const int t = threadIdx.x;
  const int w = t >> 6, l = t & 63, q = l >> 4, r16 = l & 15;
  const int m0 = blockIdx.x * 64;
  const int side  = blockIdx.y >> 1;
  const int nhalf = blockIdx.y & 1;

  f32x4 acc[4][4];
  proj_accum4(sB, Wl, m0, side, nhalf, w, q, r16, acc);

  if (side == 0){
    #pragma unroll
    for (int mi=0;mi<4;mi++){
      #pragma unroll
      for (int p=0;p<2;p++){
        int ch = w*64 + (nhalf*2+p)*16 + r16;
        #pragma unroll
        for (int r=0;r<4;r++){
          int row = m0 + mi*16 + q*4 + r;
          Pdst[(size_t)row*256 + ch] = packbf(acc[mi][2*p][r], acc[mi][2*p+1][r]);
        }
      }
    }
  } else {
    #pragma unroll
    for (int p=0;p<2;p++){
      int ch = w*64 + (nhalf*2+p)*16 + r16;
      float mf = __uint_as_float(scaleU[ch]);
      float ms = __uint_as_float(scaleU[256 + ch]);
      float invF = mf > 0.f ? 127.f/(MARG*mf) : 0.f;
      float invS = ms > 0.f ? 127.f/(MARG*ms) : 0.f;
      #pragma unroll
      for (int mi=0;mi<4;mi++)
        #pragma unroll
        for (int r=0;r<4;r++){
          int row = m0 + mi*16 + q*4 + r;
          int qfi = (int)(fminf(fmaxf(rintf(acc[mi][2*p][r]   * invF), -127.f), 127.f)) + 128;
          int qsi = (int)(fminf(fmaxf(rintf(acc[mi][2*p+1][r] * invS), -127.f), 127.f)) + 128;
          Psrc8[(size_t)row*256 + ch] = (u16)(qfi | (qsi << 8));
        }
    }
  }
}

// ---------------------------------------------------------------------------
// CSR edge aggregation: 2 nodes per block, 128 threads per node, 2 channels
// per thread. CHUNK-8 double-buffered prefetch.
// ---------------------------------------------------------------------------
#define L2E 1.442695041f
#define LN2 0.6931471806f

struct EChunk {
  u32  pv[CHUNK];
  uint2 tv[CHUNK];
};

__device__ __forceinline__ void load_chunk(
    EChunk& e, const u32* __restrict__ recRow, int base, int deg,
    const u32* __restrict__ Psrc32, const uint2* __restrict__ TFS2, u32 c2)
{
  #pragma unroll
  for (int j=0;j<CHUNK;j++){
    int idx = base + j;
    int li = idx < deg ? idx : deg-1;     // clamp; invalid slots masked in math
    u32 r = recRow[li];
    e.pv[j] = Psrc32[((r & 0xffffu) << 7) | c2];
    e.tv[j] = TFS2 [((r >> 16)     << 7) | c2];
  }
}

__global__ __launch_bounds__(256) void csr_edge_kernel(
    const uint2* __restrict__ Pdst2, const u32* __restrict__ Psrc32,
    u32* __restrict__ sB32, const uint2* __restrict__ TFS2,
    const float* __restrict__ scaleF,
    const int* __restrict__ rowptr, const u32* __restrict__ recP,
    int do_leaky)
{
  const u32 t = threadIdx.x;
  const u32 c2 = t & 127;
  const int node = blockIdx.x*2 + (int)(t >> 7);
  const int r0 = rowptr[node];
  const int deg = rowptr[node+1] - r0;
  const u32* recRow = recP + r0;

  const float2 sfp = reinterpret_cast<const float2*>(scaleF)[c2];
  const float2 ssp = reinterpret_cast<const float2*>(scaleF + 256)[c2];
  const float sfc0 = sfp.x*(MARG/127.f), sfc1 = sfp.y*(MARG/127.f);
  const float ssc0 = ssp.x*(MARG/127.f), ssc1 = ssp.y*(MARG/127.f);

  uint2 pd = Pdst2[(size_t)node*128 + c2];
  const float Pg0 = lo16(pd.x) - 128.f*sfc0;
  const float Pc0 = hi16(pd.x) - 128.f*ssc0;
  const float Pg1 = lo16(pd.y) - 128.f*sfc1;
  const float Pc1 = hi16(pd.y) - 128.f*ssc1;

  float acc0 = 0.f, acc1 = 0.f;

  if (deg > 0){
    EChunk A, B;
    load_chunk(A, recRow, 0, deg, Psrc32, TFS2, c2);
    const int nch = (deg + CHUNK - 1) / CHUNK;
    for (int c=0; c<nch; c++){
      const int base = c*CHUNK;
      if (c+1 < nch) load_chunk(B, recRow, base+CHUNK, deg, Psrc32, TFS2, c2);
      #pragma unroll
      for (int j=0;j<CHUNK;j++){
        u32 pv = A.pv[j]; uint2 tv = A.tv[j];
        float fq0 = (float)(pv & 0xffu);
        float sq0 = (float)((pv >> 8) & 0xffu);
        float fq1 = (float)((pv >> 16) & 0xffu);
        float sq1 = (float)(pv >> 24);
        float gf0 = fmaf(sfc0, fq0, Pg0 + lo16(tv.x));
        float gs0 = fmaf(ssc0, sq0, Pc0 + hi16(tv.x));
        float gf1 = fmaf(sfc1, fq1, Pg1 + lo16(tv.y));
        float gs1 = fmaf(ssc1, sq1, Pc1 + hi16(tv.y));
        float e0 = __builtin_amdgcn_exp2f(-L2E*gf0);
        float e1 = __builtin_amdgcn_exp2f(-L2E*gf1);
        float gate0 = __builtin_amdgcn_rcpf(1.f + e0);
        float gate1 = __builtin_amdgcn_rcpf(1.f + e1);
        float x0 = __builtin_amdgcn_exp2f(-L2E*fabsf(gs0));
        float x1 = __builtin_amdgcn_exp2f(-L2E*fabsf(gs1));
        float sp0 = fmaxf(gs0, 0.f) + LN2*__builtin_amdgcn_logf(1.f + x0);
        float sp1 = fmaxf(gs1, 0.f) + LN2*__builtin_amdgcn_logf(1.f + x1);
        float m0 = gate0*sp0, m1 = gate1*sp1;
        if (base + j < deg){ acc0 += m0; acc1 += m1; }
      }
      A = B;
    }
  }

  u32 old = sB32[(size_t)node*128 + c2];
  float v0 = bf2f((u16)(old & 0xffffu)) + acc0;
  float v1 = bf2f((u16)(old >> 16))     + acc1;
  if (do_leaky){ v0 = leakyf(v0); v1 = leakyf(v1); }
  sB32[(size_t)node*128 + c2] = (u32)f2bf(v0) | ((u32)f2bf(v1) << 16);
}

// ---------------------------------------------------------------------------
// Pool + head (unchanged)
// ---------------------------------------------------------------------------
__global__ __launch_bounds__(256) void pool_kernel(
    const u16* __restrict__ sB, const int* __restrict__ batch, float* __restrict__ y)
{
  const int t = threadIdx.x;
  int n0 = blockIdx.x * 64;
  int nend = min(n0 + 64, N_NODES);
  float acc = 0.f; int cur = -1;
  for (int n=n0; n<nend; n++){
    int g = batch[n];
    if (g != cur){
      if (cur >= 0) atomicAdd(&y[cur*256 + t], acc);
      acc = 0.f; cur = g;
    }
    acc += bf2f(sB[(size_t)n*256 + t]);
  }
  if (cur >= 0) atomicAdd(&y[cur*256 + t], acc);
}

__global__ __launch_bounds__(256) void desc_kernel(
    const float* __restrict__ y,
    const float* __restrict__ w1, const float* __restrict__ b1,
    const float* __restrict__ w2, const float* __restrict__ b2,
    float* __restrict__ out)
{
  __shared__ float yS[256];
  __shared__ float red[256];
  const int g = blockIdx.x, t = threadIdx.x;
  yS[t] = y[g*256 + t];
  __syncthreads();
  float acc = b1[t];
  for (int k4=0;k4<256;k4+=4){
    float4 v = *reinterpret_cast<const float4*>(&yS[k4]);
    acc += v.x*w1[(k4+0)*256+t] + v.y*w1[(k4+1)*256+t]
         + v.z*w1[(k4+2)*256+t] + v.w*w1[(k4+3)*256+t];
  }
  red[t] = fmaxf(acc, 0.f) * w2[t];
  __syncthreads();
  for (int off=128; off>0; off>>=1){
    if (t < off) red[t] += red[t+off];
    __syncthreads();
  }
  if (t == 0) out[g] = red[0] + b2[0];
}

// ---------------------------------------------------------------------------
extern "C" void kernel_launch(void* const* d_in, const int* in_sizes, int n_in,
                              void* d_out, int out_size, void* d_ws, size_t ws_size,
                              hipStream_t stream)
{
  const float* x    = (const float*)d_in[0];
  const float* fs   = (const float*)d_in[1];
  const float* fn   = (const float*)d_in[2];
  const float* act  = (const float*)d_in[3];
  const float* elen = (const float*)d_in[4];
  const float* ew1  = (const float*)d_in[5];
  const float* eb1  = (const float*)d_in[6];
  const float* ew2  = (const float*)d_in[7];
  const float* eb2  = (const float*)d_in[8];
  const float* ew3  = (const float*)d_in[9];
  const float* eb3  = (const float*)d_in[10];
  const float* aw   = (const float*)d_in[11];
  const float* ab   = (const float*)d_in[12];
  const float* cwf  = (const float*)d_in[13];
  const float* cbf  = (const float*)d_in[14];
  const float* cws  = (const float*)d_in[15];
  const float* cbs  = (const float*)d_in[16];
  const float* dw1  = (const float*)d_in[17];
  const float* db1  = (const float*)d_in[18];
  const float* dw2  = (const float*)d_in[19];
  const float* db2  = (const float*)d_in[20];
  const int*   ei   = (const int*)d_in[21];
  const int*   batch= (const int*)d_in[22];
  float* out = (float*)d_out;

  char* ws = (char*)d_ws;
  size_t off = 0;
  auto carve = [&](size_t bytes)->char*{
    char* p = ws + off; off += (bytes + 255) & ~(size_t)255; return p;
  };
  u16*  sB     = (u16*) carve((size_t)NPAD*256*2);
  u32*  Pdst   = (u32*) carve((size_t)NPAD*256*4);
  u16*  Psrc8  = (u16*) carve((size_t)NPAD*256*2);
  u16*  Wpk    = (u16*) carve((size_t)3*32*1024*8*2);
  u16*  w1pk   = (u16*) carve((size_t)1024*8*2);
  u16*  w2pk   = (u16*) carve((size_t)8192*8*2);
  u16*  w3pk   = (u16*) carve((size_t)4096*8*2);
  u32*  TFS    = (u32*) carve((size_t)3*NQ*256*4);
  u32*  scaleU = (u32*) carve((size_t)3*512*4);
  int*  rowptr = (int*) carve((size_t)(N_NODES+1)*4);
  int*  cursor = (int*) carve((size_t)N_NODES*4);
  int*  cnt    = (int*) carve((size_t)N_NODES*4);
  int*  partial= (int*) carve(256*4);
  u32*  recP   = (u32*) carve((size_t)N_EDGES*4);
  float* y     = (float*)carve((size_t)G_GRAPHS*256*4);
  if (off > ws_size) return;

  hipMemsetAsync(cnt, 0, (size_t)N_NODES*4, stream);
  hipMemsetAsync(scaleU, 0, (size_t)3*512*4, stream);
  hipMemsetAsync(y, 0, (size_t)G_GRAPHS*256*4, stream);

  const int EB = (N_EDGES + 255)/256;          // 3125
  const int SB = (N_NODES + 255)/256;          // 196

  init_kernel<<<436 + 3*NQ + EB, 256, 0, stream>>>(
      cwf, cws, cbf, cbs, ew1, ew2, ew3, ei,
      Wpk, w1pk, w2pk, w3pk, TFS, cnt);
  embed_kernel<<<NPAD/32, 256, 0, stream>>>(x, fs, fn, act,
      w1pk, eb1, w2pk, eb2, w3pk, eb3, aw, ab, sB);

  scan1_kernel<<<SB, 256, 0, stream>>>(cnt, rowptr, partial);
  scan2_kernel<<<1, 256, 0, stream>>>(partial, SB);
  scan3_kernel<<<SB, 256, 0, stream>>>(rowptr, partial, cursor);
  scatter_kernel<<<EB, 256, 0, stream>>>(ei, elen, cursor, recP);

  for (int l=0; l<3; l++){
    const u16* Wl = Wpk + (size_t)l*32*1024*8;
    u32* scaleL = scaleU + (size_t)l*512;
    proj_scale_kernel<<<dim3(97, 2), 256, 0, stream>>>(sB, Wl, scaleL);
    proj_main_kernel<<<dim3(NPAD/64, 4), 256, 0, stream>>>(
        sB, Wl, Pdst, Psrc8, scaleL);
    csr_edge_kernel<<<N_NODES/2, 256, 0, stream>>>(
        (const uint2*)Pdst, (const u32*)Psrc8, (u32*)sB,
        (const uint2*)(TFS + (size_t)l*NQ*256), (const float*)scaleL,
        rowptr, recP, (l<2) ? 1 : 0);
  }

  pool_kernel<<<(N_NODES+63)/64, 256, 0, stream>>>(sB, batch, y);
  desc_kernel<<<G_GRAPHS, 256, 0, stream>>>(y, dw1, db1, dw2, db2, out);
}

// Round 11
// 846.636 us; speedup vs baseline: 1.0337x; 1.0337x over previous
//
#include <hip/hip_runtime.h>
#include <hip/hip_bf16.h>

#define N_NODES 50000
#define NPAD    50048
#define N_EDGES 800000
#define EDIM 26
#define DXF 28
#define G_GRAPHS 64
#define NQ 2048
#define MARG 1.2f
#define CHUNK 6

typedef __attribute__((ext_vector_type(8))) short short8v;
typedef __attribute__((ext_vector_type(4))) float f32x4;
typedef unsigned short u16;
typedef unsigned int u32;

__device__ __forceinline__ float leakyf(float x){ return x >= 0.f ? x : 0.01f*x; }
__device__ __forceinline__ u16 f2bf(float f){
  __hip_bfloat16 h = __float2bfloat16(f);
  return __builtin_bit_cast(u16, h);
}
__device__ __forceinline__ float bf2f(u16 u){
  return __builtin_bit_cast(float, (u32)u << 16);
}
__device__ __forceinline__ u32 packbf(float a, float b){
  return (u32)f2bf(a) | ((u32)f2bf(b) << 16);
}
__device__ __forceinline__ float lo16(u32 v){ return __builtin_bit_cast(float, v << 16); }
__device__ __forceinline__ float hi16(u32 v){ return __builtin_bit_cast(float, v & 0xffff0000u); }

// ---------------------------------------------------------------------------
// init: fused prep (weight packing) + tfs (edge-logit table) + hist.
// block ranges: [0,436) prep, [436,6580) tfs, [6580,9705) hist.
// ---------------------------------------------------------------------------
__global__ __launch_bounds__(256) void init_kernel(
    const float* __restrict__ cwf, const float* __restrict__ cws,
    const float* __restrict__ cbf, const float* __restrict__ cbs,
    const float* __restrict__ ew1, const float* __restrict__ ew2,
    const float* __restrict__ ew3,
    const int* __restrict__ ei,
    u16* __restrict__ Wpk, u16* __restrict__ w1pk,
    u16* __restrict__ w2pk, u16* __restrict__ w3pk,
    u32* __restrict__ TFS, int* __restrict__ cnt)
{
  const int b = blockIdx.x;
  if (b < 436){
    int tid = b*256 + threadIdx.x;
    u16 out[8];
    if (tid < 98304){
      int nn  = tid & 1023;
      int kb  = (tid >> 10) & 31;
      int lyr = tid >> 15;
      int side = nn >> 9, g = (nn >> 4) & 31, r = nn & 15;
      int type = g & 1, ch = (g >> 1)*16 + r;
      const float* W = (type ? cws : cwf) + (size_t)lyr*538*256;
      #pragma unroll
      for (int j=0;j<8;j++)
        out[j] = f2bf(W[(size_t)(side*256 + kb*8 + j)*256 + ch]);
      *reinterpret_cast<uint4*>(&Wpk[(size_t)tid*8]) = *reinterpret_cast<uint4*>(out);
    } else if (tid < 99328){
      int i = tid - 98304;  int kq = i >> 8, col = i & 255;
      #pragma unroll
      for (int j=0;j<8;j++) out[j] = f2bf(ew1[(kq*8+j)*256 + col]);
      *reinterpret_cast<uint4*>(&w1pk[(size_t)i*8]) = *reinterpret_cast<uint4*>(out);
    } else if (tid < 107520){
      int i = tid - 99328;  int kb = i >> 8, col = i & 255;
      #pragma unroll
      for (int j=0;j<8;j++) out[j] = f2bf(ew2[(kb*8+j)*256 + col]);
      *reinterpret_cast<uint4*>(&w2pk[(size_t)i*8]) = *reinterpret_cast<uint4*>(out);
    } else if (tid < 111616){
      int i = tid - 107520; int kb = i >> 7, col = i & 127;
      #pragma unroll
      for (int j=0;j<8;j++) out[j] = f2bf(ew3[(kb*8+j)*128 + col]);
      *reinterpret_cast<uint4*>(&w3pk[(size_t)i*8]) = *reinterpret_cast<uint4*>(out);
    }
  } else if (b < 6580){
    int bi = b - 436;
    int q = bi & (NQ-1);
    int lyr = bi >> 11;
    int c = threadIdx.x;
    const float* wf = cwf + (size_t)lyr*538*256 + (size_t)512*256;
    const float* ws = cws + (size_t)lyr*538*256 + (size_t)512*256;
    float f = cbf[lyr*256 + c], s = cbs[lyr*256 + c];
    float len = (float)q * (5.f/NQ);
    for (int k=0;k<EDIM;k++){
      float d = len - 0.2f*(float)k;
      float g = __expf(-25.f*d*d);
      f += g * wf[k*256 + c];
      s += g * ws[k*256 + c];
    }
    TFS[((size_t)lyr*NQ + q)*256 + c] = packbf(f, s);
  } else {
    int e = (b - 6580)*256 + threadIdx.x;
    if (e < N_EDGES) atomicAdd(&cnt[ei[N_EDGES + e]], 1);
  }
}

// ---------------------------------------------------------------------------
// Embed (MFMA): 32 nodes per block.
// ---------------------------------------------------------------------------
__global__ __launch_bounds__(256) void embed_kernel(
    const float* __restrict__ x, const float* __restrict__ fs,
    const float* __restrict__ fn, const float* __restrict__ act,
    const u16* __restrict__ w1pk, const float* __restrict__ eb1,
    const u16* __restrict__ w2pk, const float* __restrict__ eb2,
    const u16* __restrict__ w3pk, const float* __restrict__ eb3,
    const float* __restrict__ aw,  const float* __restrict__ ab,
    u16* __restrict__ sB)
{
  __shared__ u16 inA[32*32];
  __shared__ float actS[32*4];
  __shared__ u16 h1[32*256];
  __shared__ u16 h2[32*256];
  const int t = threadIdx.x;
  const int w = t >> 6, l = t & 63, q = l >> 4, r16 = l & 15;
  const int node0 = blockIdx.x * 32;

  for (int idx=t; idx<1024; idx+=256){
    int n = idx >> 5, k = idx & 31;
    int node = node0 + n;
    float v = 0.f;
    if (node < N_NODES){
      if (k < DXF)      v = x[node*DXF + k];
      else if (k < 31)  v = fs[node*3 + (k - DXF)];
      else              v = fn[node];
    }
    inA[idx] = f2bf(v);
  }
  { int n = t >> 2, k = t & 3;
    float v = 0.f;
    if (n < 32 && k < 3 && node0 + n < N_NODES) v = act[(node0+n)*3 + k];
    if (n < 32) actS[t] = v; }
  __syncthreads();

  f32x4 acc[2][4];
  #pragma unroll
  for (int mi=0;mi<2;mi++)
    #pragma unroll
    for (int ni=0;ni<4;ni++){ acc[mi][ni][0]=0;acc[mi][ni][1]=0;acc[mi][ni][2]=0;acc[mi][ni][3]=0; }
  {
    short8v a[2], b[4];
    #pragma unroll
    for (int mi=0;mi<2;mi++)
      a[mi] = *reinterpret_cast<const short8v*>(&inA[(mi*16+r16)*32 + q*8]);
    #pragma unroll
    for (int ni=0;ni<4;ni++)
      b[ni] = *reinterpret_cast<const short8v*>(&w1pk[((size_t)q*256 + w*64 + ni*16 + r16)*8]);
    #pragma unroll
    for (int mi=0;mi<2;mi++)
      #pragma unroll
      for (int ni=0;ni<4;ni++)
        acc[mi][ni] = __builtin_amdgcn_mfma_f32_16x16x32_bf16(a[mi], b[ni], acc[mi][ni], 0,0,0);
  }
  #pragma unroll
  for (int ni=0;ni<4;ni++){
    int col = w*64 + ni*16 + r16;
    float bias = eb1[col];
    #pragma unroll
    for (int mi=0;mi<2;mi++)
      #pragma unroll
      for (int r=0;r<4;r++){
        int row = mi*16 + q*4 + r;
        h1[(row*256 + col) ^ ((row&7)<<3)] = f2bf(leakyf(acc[mi][ni][r] + bias));
      }
  }
  __syncthreads();

  #pragma unroll
  for (int mi=0;mi<2;mi++)
    #pragma unroll
    for (int ni=0;ni<4;ni++){ acc[mi][ni][0]=0;acc[mi][ni][1]=0;acc[mi][ni][2]=0;acc[mi][ni][3]=0; }
  for (int ks=0;ks<8;ks++){
    short8v a[2], b[4];
    #pragma unroll
    for (int mi=0;mi<2;mi++){
      int row = mi*16 + r16;
      a[mi] = *reinterpret_cast<const short8v*>(&h1[(row*256 + ks*32 + q*8) ^ ((row&7)<<3)]);
    }
    #pragma unroll
    for (int ni=0;ni<4;ni++)
      b[ni] = *reinterpret_cast<const short8v*>(&w2pk[((size_t)(ks*4+q)*256 + w*64 + ni*16 + r16)*8]);
    #pragma unroll
    for (int mi=0;mi<2;mi++)
      #pragma unroll
      for (int ni=0;ni<4;ni++)
        acc[mi][ni] = __builtin_amdgcn_mfma_f32_16x16x32_bf16(a[mi], b[ni], acc[mi][ni], 0,0,0);
  }
  #pragma unroll
  for (int ni=0;ni<4;ni++){
    int col = w*64 + ni*16 + r16;
    float bias = eb2[col];
    #pragma unroll
    for (int mi=0;mi<2;mi++)
      #pragma unroll
      for (int r=0;r<4;r++){
        int row = mi*16 + q*4 + r;
        h2[(row*256 + col) ^ ((row&7)<<3)] = f2bf(leakyf(acc[mi][ni][r] + bias));
      }
  }
  __syncthreads();

  if (w < 2){
    #pragma unroll
    for (int mi=0;mi<2;mi++)
      #pragma unroll
      for (int ni=0;ni<4;ni++){ acc[mi][ni][0]=0;acc[mi][ni][1]=0;acc[mi][ni][2]=0;acc[mi][ni][3]=0; }
    for (int ks=0;ks<8;ks++){
      short8v a[2], b[4];
      #pragma unroll
      for (int mi=0;mi<2;mi++){
        int row = mi*16 + r16;
        a[mi] = *reinterpret_cast<const short8v*>(&h2[(row*256 + ks*32 + q*8) ^ ((row&7)<<3)]);
      }
      #pragma unroll
      for (int ni=0;ni<4;ni++)
        b[ni] = *reinterpret_cast<const short8v*>(&w3pk[((size_t)(ks*4+q)*128 + w*64 + ni*16 + r16)*8]);
      #pragma unroll
      for (int mi=0;mi<2;mi++)
        #pragma unroll
        for (int ni=0;ni<4;ni++)
          acc[mi][ni] = __builtin_amdgcn_mfma_f32_16x16x32_bf16(a[mi], b[ni], acc[mi][ni], 0,0,0);
    }
    #pragma unroll
    for (int ni=0;ni<4;ni++){
      int col = w*64 + ni*16 + r16;
      float bias = eb3[col];
      #pragma unroll
      for (int mi=0;mi<2;mi++)
        #pragma unroll
        for (int r=0;r<4;r++){
          int row = mi*16 + q*4 + r;
          sB[(size_t)(node0+row)*256 + col] = f2bf(leakyf(acc[mi][ni][r] + bias));
        }
    }
  } else {
    int c = t - 128;
    float w0 = aw[c], w1 = aw[128+c], w2 = aw[256+c], bb = ab[c];
    for (int n=0;n<32;n++){
      float v = bb + actS[n*4]*w0 + actS[n*4+1]*w1 + actS[n*4+2]*w2;
      sB[(size_t)(node0+n)*256 + 128 + c] = f2bf(v);
    }
  }
}

// ---------------------------------------------------------------------------
// CSR build scans + scatter
// ---------------------------------------------------------------------------
__global__ __launch_bounds__(256) void scan1_kernel(
    const int* __restrict__ cnt, int* __restrict__ rowptr, int* __restrict__ partial){
  __shared__ int sd[256];
  int t = threadIdx.x; int idx = blockIdx.x*256 + t;
  int v = (idx < N_NODES) ? cnt[idx] : 0;
  sd[t] = v; __syncthreads();
  for (int off=1; off<256; off<<=1){
    int x2 = (t>=off) ? sd[t-off] : 0;
    __syncthreads();
    sd[t] += x2; __syncthreads();
  }
  if (idx < N_NODES) rowptr[idx] = sd[t] - v;
  if (t == 255) partial[blockIdx.x] = sd[255];
}

__global__ __launch_bounds__(256) void scan2_kernel(int* __restrict__ partial, int nb){
  __shared__ int sd[256];
  int t = threadIdx.x;
  int v = (t<nb) ? partial[t] : 0;
  sd[t] = v; __syncthreads();
  for (int off=1; off<256; off<<=1){
    int x2 = (t>=off) ? sd[t-off] : 0;
    __syncthreads();
    sd[t] += x2; __syncthreads();
  }
  if (t<nb) partial[t] = sd[t] - v;
}

__global__ __launch_bounds__(256) void scan3_kernel(
    int* __restrict__ rowptr, const int* __restrict__ partial, int* __restrict__ cursor){
  int idx = blockIdx.x*256 + threadIdx.x;
  if (idx < N_NODES){
    int v = rowptr[idx] + partial[blockIdx.x];
    rowptr[idx] = v; cursor[idx] = v;
  }
  if (idx == 0) rowptr[N_NODES] = N_EDGES;
}

__global__ __launch_bounds__(256) void scatter_kernel(
    const int* __restrict__ ei, const float* __restrict__ elen,
    int* __restrict__ cursor, u32* __restrict__ recP)
{
  int e = blockIdx.x*256 + threadIdx.x;
  if (e >= N_EDGES) return;
  int d = ei[N_EDGES + e];
  int pos = atomicAdd(&cursor[d], 1);
  int qq = (int)rintf(elen[e] * ((float)NQ/5.f));
  qq = min(max(qq,0), NQ-1);
  recP[pos] = (u32)ei[e] | ((u32)qq << 16);
}

// ---------------------------------------------------------------------------
// Proj: quadrant MFMA accumulate (64 rows x 256 packed cols), acc = 64 VGPR.
// ---------------------------------------------------------------------------
__device__ __forceinline__ void proj_accum4(
    const u16* __restrict__ sB, const u16* __restrict__ Wl,
    int m0, int side, int nhalf, int w, int q, int r16, f32x4 acc[4][4])
{
  #pragma unroll
  for (int mi=0;mi<4;mi++)
    #pragma unroll
    for (int ni=0;ni<4;ni++){ acc[mi][ni][0]=0;acc[mi][ni][1]=0;acc[mi][ni][2]=0;acc[mi][ni][3]=0; }
  for (int ks=0; ks<8; ks++){
    short8v a[4], b[4];
    #pragma unroll
    for (int mi=0;mi<4;mi++)
      a[mi] = *reinterpret_cast<const short8v*>(&sB[(size_t)(m0+mi*16+r16)*256 + ks*32 + q*8]);
    #pragma unroll
    for (int ni=0;ni<4;ni++)
      b[ni] = *reinterpret_cast<const short8v*>(
        &Wl[((size_t)(ks*4+q)*1024 + side*512 + w*128 + (nhalf*4+ni)*16 + r16)*8]);
    #pragma unroll
    for (int mi=0;mi<4;mi++)
      #pragma unroll
      for (int ni=0;ni<4;ni++)
        acc[mi][ni] = __builtin_amdgcn_mfma_f32_16x16x32_bf16(a[mi], b[ni], acc[mi][ni], 0,0,0);
  }
}

// scale pass: sampled tiles (every 8th), src side only; per-channel absmax.
__global__ __launch_bounds__(256) void proj_scale_kernel(
    const u16* __restrict__ sB, const u16* __restrict__ Wl,
    u32* __restrict__ scaleU)
{
  __shared__ u32 smax[512];
  const int t = threadIdx.x;
  const int w = t >> 6, l = t & 63, q = l >> 4, r16 = l & 15;
  const int m0 = blockIdx.x * 512;
  const int nhalf = blockIdx.y;
  for (int i=t;i<512;i+=256) smax[i] = 0;
  __syncthreads();

  f32x4 acc[4][4];
  proj_accum4(sB, Wl, m0, 1, nhalf, w, q, r16, acc);

  #pragma unroll
  for (int p=0;p<2;p++){
    int ch = w*64 + (nhalf*2+p)*16 + r16;
    float mf = 0.f, ms = 0.f;
    #pragma unroll
    for (int mi=0;mi<4;mi++)
      #pragma unroll
      for (int r=0;r<4;r++){
        mf = fmaxf(mf, fabsf(acc[mi][2*p][r]));
        ms = fmaxf(ms, fabsf(acc[mi][2*p+1][r]));
      }
    atomicMax(&smax[ch],       __float_as_uint(mf));
    atomicMax(&smax[256 + ch], __float_as_uint(ms));
  }
  __syncthreads();
  for (int i=t;i<512;i+=256) atomicMax(&scaleU[i], smax[i]);
}

// main proj: grid (NPAD/64, 4); y>>1 = side (0 dst bf16, 1 src int8), y&1 = n-half.
__global__ __launch_bounds__(256) void proj_main_kernel(
    const u16* __restrict__ sB, const u16* __restrict__ Wl,
    u32* __restrict__ Pdst, u16* __restrict__ Psrc8,
    const u32* __restrict__ scaleU)
{
  const int t = threadIdx.x;
  const int w = t >> 6, l = t & 63, q = l >> 4, r16 = l & 15;
  const int m0 = blockIdx.x * 64;
  const int side  = blockIdx.y >> 1;
  const int nhalf = blockIdx.y & 1;

  f32x4 acc[4][4];
  proj_accum4(sB, Wl, m0, side, nhalf, w, q, r16, acc);

  if (side == 0){
    #pragma unroll
    for (int mi=0;mi<4;mi++){
      #pragma unroll
      for (int p=0;p<2;p++){
        int ch = w*64 + (nhalf*2+p)*16 + r16;
        #pragma unroll
        for (int r=0;r<4;r++){
          int row = m0 + mi*16 + q*4 + r;
          Pdst[(size_t)row*256 + ch] = packbf(acc[mi][2*p][r], acc[mi][2*p+1][r]);
        }
      }
    }
  } else {
    #pragma unroll
    for (int p=0;p<2;p++){
      int ch = w*64 + (nhalf*2+p)*16 + r16;
      float mf = __uint_as_float(scaleU[ch]);
      float ms = __uint_as_float(scaleU[256 + ch]);
      float invF = mf > 0.f ? 127.f/(MARG*mf) : 0.f;
      float invS = ms > 0.f ? 127.f/(MARG*ms) : 0.f;
      #pragma unroll
      for (int mi=0;mi<4;mi++)
        #pragma unroll
        for (int r=0;r<4;r++){
          int row = m0 + mi*16 + q*4 + r;
          int qfi = (int)(fminf(fmaxf(rintf(acc[mi][2*p][r]   * invF), -127.f), 127.f)) + 128;
          int qsi = (int)(fminf(fmaxf(rintf(acc[mi][2*p+1][r] * invS), -127.f), 127.f)) + 128;
          Psrc8[(size_t)row*256 + ch] = (u16)(qfi | (qsi << 8));
        }
    }
  }
}

// ---------------------------------------------------------------------------
// CSR edge aggregation: 2 nodes per block, 128 threads per node, 2 channels
// per thread. CHUNK-6 double-buffered prefetch (measured optimum).
// ---------------------------------------------------------------------------
#define L2E 1.442695041f
#define LN2 0.6931471806f

struct EChunk {
  u32  pv[CHUNK];
  uint2 tv[CHUNK];
};

__device__ __forceinline__ void load_chunk(
    EChunk& e, const u32* __restrict__ recRow, int base, int deg,
    const u32* __restrict__ Psrc32, const uint2* __restrict__ TFS2, u32 c2)
{
  #pragma unroll
  for (int j=0;j<CHUNK;j++){
    int idx = base + j;
    int li = idx < deg ? idx : deg-1;     // clamp; invalid slots masked in math
    u32 r = recRow[li];
    e.pv[j] = Psrc32[((r & 0xffffu) << 7) | c2];
    e.tv[j] = TFS2 [((r >> 16)     << 7) | c2];
  }
}

__global__ __launch_bounds__(256) void csr_edge_kernel(
    const uint2* __restrict__ Pdst2, const u32* __restrict__ Psrc32,
    u32* __restrict__ sB32, const uint2* __restrict__ TFS2,
    const float* __restrict__ scaleF,
    const int* __restrict__ rowptr, const u32* __restrict__ recP,
    int do_leaky)
{
  const u32 t = threadIdx.x;
  const u32 c2 = t & 127;
  const int node = blockIdx.x*2 + (int)(t >> 7);
  const int r0 = rowptr[node];
  const int deg = rowptr[node+1] - r0;
  const u32* recRow = recP + r0;

  const float2 sfp = reinterpret_cast<const float2*>(scaleF)[c2];
  const float2 ssp = reinterpret_cast<const float2*>(scaleF + 256)[c2];
  const float sfc0 = sfp.x*(MARG/127.f), sfc1 = sfp.y*(MARG/127.f);
  const float ssc0 = ssp.x*(MARG/127.f), ssc1 = ssp.y*(MARG/127.f);

  uint2 pd = Pdst2[(size_t)node*128 + c2];
  const float Pg0 = lo16(pd.x) - 128.f*sfc0;
  const float Pc0 = hi16(pd.x) - 128.f*ssc0;
  const float Pg1 = lo16(pd.y) - 128.f*sfc1;
  const float Pc1 = hi16(pd.y) - 128.f*ssc1;

  float acc0 = 0.f, acc1 = 0.f;

  if (deg > 0){
    EChunk A, B;
    load_chunk(A, recRow, 0, deg, Psrc32, TFS2, c2);
    const int nch = (deg + CHUNK - 1) / CHUNK;
    for (int c=0; c<nch; c++){
      const int base = c*CHUNK;
      if (c+1 < nch) load_chunk(B, recRow, base+CHUNK, deg, Psrc32, TFS2, c2);
      #pragma unroll
      for (int j=0;j<CHUNK;j++){
        u32 pv = A.pv[j]; uint2 tv = A.tv[j];
        float fq0 = (float)(pv & 0xffu);
        float sq0 = (float)((pv >> 8) & 0xffu);
        float fq1 = (float)((pv >> 16) & 0xffu);
        float sq1 = (float)(pv >> 24);
        float gf0 = fmaf(sfc0, fq0, Pg0 + lo16(tv.x));
        float gs0 = fmaf(ssc0, sq0, Pc0 + hi16(tv.x));
        float gf1 = fmaf(sfc1, fq1, Pg1 + lo16(tv.y));
        float gs1 = fmaf(ssc1, sq1, Pc1 + hi16(tv.y));
        float e0 = __builtin_amdgcn_exp2f(-L2E*gf0);
        float e1 = __builtin_amdgcn_exp2f(-L2E*gf1);
        float gate0 = __builtin_amdgcn_rcpf(1.f + e0);
        float gate1 = __builtin_amdgcn_rcpf(1.f + e1);
        float x0 = __builtin_amdgcn_exp2f(-L2E*fabsf(gs0));
        float x1 = __builtin_amdgcn_exp2f(-L2E*fabsf(gs1));
        float sp0 = fmaxf(gs0, 0.f) + LN2*__builtin_amdgcn_logf(1.f + x0);
        float sp1 = fmaxf(gs1, 0.f) + LN2*__builtin_amdgcn_logf(1.f + x1);
        float m0 = gate0*sp0, m1 = gate1*sp1;
        if (base + j < deg){ acc0 += m0; acc1 += m1; }
      }
      A = B;
    }
  }

  u32 old = sB32[(size_t)node*128 + c2];
  float v0 = bf2f((u16)(old & 0xffffu)) + acc0;
  float v1 = bf2f((u16)(old >> 16))     + acc1;
  if (do_leaky){ v0 = leakyf(v0); v1 = leakyf(v1); }
  sB32[(size_t)node*128 + c2] = (u32)f2bf(v0) | ((u32)f2bf(v1) << 16);
}

// ---------------------------------------------------------------------------
// Pool + head (unchanged)
// ---------------------------------------------------------------------------
__global__ __launch_bounds__(256) void pool_kernel(
    const u16* __restrict__ sB, const int* __restrict__ batch, float* __restrict__ y)
{
  const int t = threadIdx.x;
  int n0 = blockIdx.x * 64;
  int nend = min(n0 + 64, N_NODES);
  float acc = 0.f; int cur = -1;
  for (int n=n0; n<nend; n++){
    int g = batch[n];
    if (g != cur){
      if (cur >= 0) atomicAdd(&y[cur*256 + t], acc);
      acc = 0.f; cur = g;
    }
    acc += bf2f(sB[(size_t)n*256 + t]);
  }
  if (cur >= 0) atomicAdd(&y[cur*256 + t], acc);
}

__global__ __launch_bounds__(256) void desc_kernel(
    const float* __restrict__ y,
    const float* __restrict__ w1, const float* __restrict__ b1,
    const float* __restrict__ w2, const float* __restrict__ b2,
    float* __restrict__ out)
{
  __shared__ float yS[256];
  __shared__ float red[256];
  const int g = blockIdx.x, t = threadIdx.x;
  yS[t] = y[g*256 + t];
  __syncthreads();
  float acc = b1[t];
  for (int k4=0;k4<256;k4+=4){
    float4 v = *reinterpret_cast<const float4*>(&yS[k4]);
    acc += v.x*w1[(k4+0)*256+t] + v.y*w1[(k4+1)*256+t]
         + v.z*w1[(k4+2)*256+t] + v.w*w1[(k4+3)*256+t];
  }
  red[t] = fmaxf(acc, 0.f) * w2[t];
  __syncthreads();
  for (int off=128; off>0; off>>=1){
    if (t < off) red[t] += red[t+off];
    __syncthreads();
  }
  if (t == 0) out[g] = red[0] + b2[0];
}

// ---------------------------------------------------------------------------
extern "C" void kernel_launch(void* const* d_in, const int* in_sizes, int n_in,
                              void* d_out, int out_size, void* d_ws, size_t ws_size,
                              hipStream_t stream)
{
  const float* x    = (const float*)d_in[0];
  const float* fs   = (const float*)d_in[1];
  const float* fn   = (const float*)d_in[2];
  const float* act  = (const float*)d_in[3];
  const float* elen = (const float*)d_in[4];
  const float* ew1  = (const float*)d_in[5];
  const float* eb1  = (const float*)d_in[6];
  const float* ew2  = (const float*)d_in[7];
  const float* eb2  = (const float*)d_in[8];
  const float* ew3  = (const float*)d_in[9];
  const float* eb3  = (const float*)d_in[10];
  const float* aw   = (const float*)d_in[11];
  const float* ab   = (const float*)d_in[12];
  const float* cwf  = (const float*)d_in[13];
  const float* cbf  = (const float*)d_in[14];
  const float* cws  = (const float*)d_in[15];
  const float* cbs  = (const float*)d_in[16];
  const float* dw1  = (const float*)d_in[17];
  const float* db1  = (const float*)d_in[18];
  const float* dw2  = (const float*)d_in[19];
  const float* db2  = (const float*)d_in[20];
  const int*   ei   = (const int*)d_in[21];
  const int*   batch= (const int*)d_in[22];
  float* out = (float*)d_out;

  char* ws = (char*)d_ws;
  size_t off = 0;
  auto carve = [&](size_t bytes)->char*{
    char* p = ws + off; off += (bytes + 255) & ~(size_t)255; return p;
  };
  u16*  sB     = (u16*) carve((size_t)NPAD*256*2);
  u32*  Pdst   = (u32*) carve((size_t)NPAD*256*4);
  u16*  Psrc8  = (u16*) carve((size_t)NPAD*256*2);
  u16*  Wpk    = (u16*) carve((size_t)3*32*1024*8*2);
  u16*  w1pk   = (u16*) carve((size_t)1024*8*2);
  u16*  w2pk   = (u16*) carve((size_t)8192*8*2);
  u16*  w3pk   = (u16*) carve((size_t)4096*8*2);
  u32*  TFS    = (u32*) carve((size_t)3*NQ*256*4);
  u32*  scaleU = (u32*) carve((size_t)3*512*4);
  int*  rowptr = (int*) carve((size_t)(N_NODES+1)*4);
  int*  cursor = (int*) carve((size_t)N_NODES*4);
  int*  cnt    = (int*) carve((size_t)N_NODES*4);
  int*  partial= (int*) carve(256*4);
  u32*  recP   = (u32*) carve((size_t)N_EDGES*4);
  float* y     = (float*)carve((size_t)G_GRAPHS*256*4);
  if (off > ws_size) return;

  hipMemsetAsync(cnt, 0, (size_t)N_NODES*4, stream);
  hipMemsetAsync(scaleU, 0, (size_t)3*512*4, stream);
  hipMemsetAsync(y, 0, (size_t)G_GRAPHS*256*4, stream);

  const int EB = (N_EDGES + 255)/256;          // 3125
  const int SB = (N_NODES + 255)/256;          // 196

  init_kernel<<<436 + 3*NQ + EB, 256, 0, stream>>>(
      cwf, cws, cbf, cbs, ew1, ew2, ew3, ei,
      Wpk, w1pk, w2pk, w3pk, TFS, cnt);
  embed_kernel<<<NPAD/32, 256, 0, stream>>>(x, fs, fn, act,
      w1pk, eb1, w2pk, eb2, w3pk, eb3, aw, ab, sB);

  scan1_kernel<<<SB, 256, 0, stream>>>(cnt, rowptr, partial);
  scan2_kernel<<<1, 256, 0, stream>>>(partial, SB);
  scan3_kernel<<<SB, 256, 0, stream>>>(rowptr, partial, cursor);
  scatter_kernel<<<EB, 256, 0, stream>>>(ei, elen, cursor, recP);

  for (int l=0; l<3; l++){
    const u16* Wl = Wpk + (size_t)l*32*1024*8;
    u32* scaleL = scaleU + (size_t)l*512;
    proj_scale_kernel<<<dim3(97, 2), 256, 0, stream>>>(sB, Wl, scaleL);
    proj_main_kernel<<<dim3(NPAD/64, 4), 256, 0, stream>>>(
        sB, Wl, Pdst, Psrc8, scaleL);
    csr_edge_kernel<<<N_NODES/2, 256, 0, stream>>>(
        (const uint2*)Pdst, (const u32*)Psrc8, (u32*)sB,
        (const uint2*)(TFS + (size_t)l*NQ*256), (const float*)scaleL,
        rowptr, recP, (l<2) ? 1 : 0);
  }

  pool_kernel<<<(N_NODES+63)/64, 256, 0, stream>>>(sB, batch, y);
  desc_kernel<<<G_GRAPHS, 256, 0, stream>>>(y, dw1, db1, dw2, db2, out);
}